// Round 13
// baseline (52.242 us; speedup 1.0000x reference)
//
#include <hip/hip_runtime.h>
#include <hip/hip_fp16.h>
#include <math.h>

#define B_ 16
#define F_ 256
#define T_ 2048
#define K_ 20
#define OUTK 21
#define NPAIR 10

typedef _Float16 half2v __attribute__((ext_vector_type(2)));
typedef float v2f __attribute__((ext_vector_type(2)));

#if __has_builtin(__builtin_amdgcn_cvt_pk_f32_fp8) && __has_builtin(__builtin_amdgcn_cvt_pk_fp8_f32)
#define HW_FP8 1
#else
#define HW_FP8 0
#endif

#if !HW_FP8
// fallback e4m3 (OCP) decode/encode — only compiled if HW cvt builtins absent
__device__ __forceinline__ float dec_fp8(unsigned v) {
    unsigned s = (v >> 7) & 1, e = (v >> 3) & 15, m = v & 7;
    float r = e ? __uint_as_float(((e + 120u) << 23) | (m << 20))
                : (float)m * 0.001953125f;  // 2^-9
    return s ? -r : r;
}
__device__ __forceinline__ unsigned enc_fp8(float x) {
    unsigned bits = __float_as_uint(x);
    unsigned s = bits >> 31;
    unsigned a = bits & 0x7fffffffu;
    float ax = __uint_as_float(a);
    unsigned r;
    if (ax < 0.015625f) {                      // subnormal (< 2^-6)
        r = (unsigned)(int)(ax * 512.f + 0.5f);
    } else {
        int e = (int)(a >> 23) - 127;
        unsigned m = a & 0x7fffffu;
        unsigned keep = m >> 20, rest = m & 0xFFFFFu;
        keep += (rest > 0x80000u) || (rest == 0x80000u && (keep & 1));
        if (keep == 8) { keep = 0; ++e; }
        r = ((unsigned)(e + 7) << 3) | keep;
    }
    return (s << 7) | r;
}
#endif

__device__ __forceinline__ unsigned pack_fp8x4(float a0, float a1, float a2, float a3) {
#if HW_FP8
    int u = 0;
    u = __builtin_amdgcn_cvt_pk_fp8_f32(a0, a1, u, false);
    u = __builtin_amdgcn_cvt_pk_fp8_f32(a2, a3, u, true);
    return (unsigned)u;
#else
    return enc_fp8(a0) | (enc_fp8(a1) << 8) | (enc_fp8(a2) << 16) | (enc_fp8(a3) << 24);
#endif
}
template <bool HI>
__device__ __forceinline__ v2f unpk_fp8(unsigned u) {
#if HW_FP8
    return __builtin_amdgcn_cvt_pk_f32_fp8((int)u, HI);
#else
    v2f r; unsigned x = HI ? (u >> 16) : u;
    r[0] = dec_fp8(x & 0xFF); r[1] = dec_fp8((x >> 8) & 0xFF);
    return r;
#endif
}

// Prep: per (b, 32-t tile) stage BOTH z and c fp32 column-tiles in LDS;
// compute exact fp32 positive logit -> out[...,0]; write unit-norm tables:
// zth (f16, for own-row zv), zf8 + cf8 (fp8 e4m3, for gathers + mask).
__global__ __launch_bounds__(256) void prep_kernel(
    const float* __restrict__ z, const float* __restrict__ c,
    ushort* __restrict__ zth, unsigned char* __restrict__ zf8,
    unsigned char* __restrict__ cf8, float* __restrict__ out)
{
    __shared__ float tz[256][33];
    __shared__ float tc[256][33];
    __shared__ float scz[32], scc[32];
    int b  = blockIdx.y;
    int t0 = blockIdx.x * 32;
    const float* zb = z + (size_t)b * F_ * T_;
    const float* cb = c + (size_t)b * F_ * (T_ + 1);
    int tl = threadIdx.x & 31;
    int fl = threadIdx.x >> 5;
#pragma unroll
    for (int i = 0; i < 32; ++i) {
        int f = i * 8 + fl;
        tz[f][tl] = zb[(size_t)f * T_ + t0 + tl];
    }
#pragma unroll
    for (int i = 0; i < 32; ++i) {
        int f = i * 8 + fl;
        tc[f][tl] = cb[(size_t)f * (T_ + 1) + t0 + tl + 1];   // drop start token
    }
    __syncthreads();
    if (threadIdx.x < 32) {
        float zn = 0.f, cn = 0.f, zc = 0.f;
#pragma unroll 8
        for (int f = 0; f < 256; ++f) {
            float a = tz[f][threadIdx.x], d = tc[f][threadIdx.x];
            zn = fmaf(a, a, zn); cn = fmaf(d, d, cn); zc = fmaf(a, d, zc);
        }
        float nz_ = sqrtf(zn), nc_ = sqrtf(cn);
        scz[threadIdx.x] = (nz_ > 0.f) ? (1.0f / nz_) : 0.f;
        scc[threadIdx.x] = (nc_ > 0.f) ? (1.0f / nc_) : 0.f;
        int bt = (b << 11) + t0 + threadIdx.x;
        out[(size_t)bt * OUTK] = (zc / fmaxf(nz_ * nc_, 1e-8f)) * 2.0f;  // exact fp32 positive
    }
    __syncthreads();
    // zth f16 unit rows: 128 lanes/row, 2 rows/iter
    {
        int l = threadIdx.x & 127, rhi = threadIdx.x >> 7;
#pragma unroll
        for (int j2 = 0; j2 < 16; ++j2) {
            int row = j2 * 2 + rhi;
            float s = scz[row];
            float a  = tz[2 * l][row] * s;
            float bb = tz[2 * l + 1][row] * s;
            unsigned u = ((unsigned)__half_as_ushort(__float2half(bb)) << 16)
                       |  (unsigned)__half_as_ushort(__float2half(a));
            ((unsigned*)(zth + ((size_t)b * T_ + t0 + row) * F_))[l] = u;
        }
    }
    // fp8 unit rows (z and c): 64 lanes/row (4 values each), 4 rows/iter
    {
        int j = threadIdx.x & 63, r4 = threadIdx.x >> 6;
#pragma unroll
        for (int it = 0; it < 8; ++it) {
            int row = it * 4 + r4;
            float sz_ = scz[row], sc_ = scc[row];
            unsigned uz = pack_fp8x4(tz[4 * j][row] * sz_, tz[4 * j + 1][row] * sz_,
                                     tz[4 * j + 2][row] * sz_, tz[4 * j + 3][row] * sz_);
            unsigned uc = pack_fp8x4(tc[4 * j][row] * sc_, tc[4 * j + 1][row] * sc_,
                                     tc[4 * j + 2][row] * sc_, tc[4 * j + 3][row] * sc_);
            ((unsigned*)(zf8 + ((size_t)b * T_ + t0 + row) * F_))[j] = uz;
            ((unsigned*)(cf8 + ((size_t)b * T_ + t0 + row) * F_))[j] = uc;
        }
    }
}

// Sum within each 32-lane half (pure VALU DPP). Valid in lane 31 (lo) / 63 (hi).
__device__ __forceinline__ float dpp_half_sum(float x) {
    x += __int_as_float(__builtin_amdgcn_mov_dpp(__float_as_int(x), 0x111, 0xF, 0xF, true)); // row_shr:1
    x += __int_as_float(__builtin_amdgcn_mov_dpp(__float_as_int(x), 0x112, 0xF, 0xF, true)); // row_shr:2
    x += __int_as_float(__builtin_amdgcn_mov_dpp(__float_as_int(x), 0x114, 0xF, 0xF, true)); // row_shr:4
    x += __int_as_float(__builtin_amdgcn_mov_dpp(__float_as_int(x), 0x118, 0xF, 0xF, true)); // row_shr:8
    x += __int_as_float(__builtin_amdgcn_mov_dpp(__float_as_int(x), 0x142, 0xF, 0xF, true)); // row_bcast:15
    return x;
}

// One 64-lane wave per (b,t): 20 negatives as 10 fp8 pair-loads (256 B/row =
// 4 lines, half of f16). Own row zv stays f16. Positive written by prep.
// Mask = bitwise fp8-row equality vs cf8 row (conservative-exact screen+verify).
__global__ __launch_bounds__(256, 8) void sim_kernel(
    const ushort* __restrict__ zth, const unsigned char* __restrict__ zf8,
    const unsigned char* __restrict__ cf8, const int* __restrict__ inds,
    float* __restrict__ out)
{
    __shared__ float sd[128];                         // 4 waves x 32 slots
    int i = blockIdx.x;                               // 8192 blocks, 4 waves each
    int b = (i & 7) | ((i >= 4096) ? 8 : 0);          // batch b on XCD b&7 (L2-resident tables)
    int wid = threadIdx.x >> 6;
    int t = (((i >> 3) & 511) << 2) + wid;
    int lane = threadIdx.x & 63;
    int hl = lane & 31;                               // pos within half
    int hi = lane >> 5;                               // which half
    int bt = __builtin_amdgcn_readfirstlane((b << 11) + t);

    const int* myinds = inds + bt * K_;
    int idxv = myinds[(lane < K_) ? lane : 0];        // lane k holds inds[k]

    uint4 zv  = ((const uint4*)(zth + (size_t)bt * F_))[hl];   // own z row (f16)
    uint2 cv8 = ((const uint2*)(cf8 + (size_t)bt * F_))[hl];   // own c row (fp8)

    const char* tbl8 = (const char*)zf8;
    unsigned zbase8  = (unsigned)(b << 11) * 256u;
    unsigned laneoff = (unsigned)hl * 8u;

    uint2 tv[NPAIR];
#pragma unroll
    for (int p = 0; p < NPAIR; ++p) {
        unsigned ilo = (unsigned)__builtin_amdgcn_readlane(idxv, 2 * p);
        unsigned ihi = (unsigned)__builtin_amdgcn_readlane(idxv, 2 * p + 1);
        unsigned off = zbase8 + (hi ? ihi : ilo) * 256u + laneoff;
        tv[p] = *(const uint2*)(tbl8 + off);
    }

    // hard scheduler fence: all 10 pair loads stay issued up-front
    __builtin_amdgcn_sched_barrier(0);

    // zv -> 8 f32 (once per wave-t)
    float zf[8];
    {
        unsigned uu[4] = {zv.x, zv.y, zv.z, zv.w};
#pragma unroll
        for (int q = 0; q < 4; ++q) {
            half2v h = __builtin_bit_cast(half2v, uu[q]);
            zf[2 * q] = (float)h[0]; zf[2 * q + 1] = (float)h[1];
        }
    }

    float dz[NPAIR];
#pragma unroll
    for (int p = 0; p < NPAIR; ++p) {
        v2f t01 = unpk_fp8<false>(tv[p].x);
        v2f t23 = unpk_fp8<true >(tv[p].x);
        v2f t45 = unpk_fp8<false>(tv[p].y);
        v2f t67 = unpk_fp8<true >(tv[p].y);
        float d = zf[0] * t01[0];
        d = fmaf(zf[1], t01[1], d);
        d = fmaf(zf[2], t23[0], d);
        d = fmaf(zf[3], t23[1], d);
        d = fmaf(zf[4], t45[0], d);
        d = fmaf(zf[5], t45[1], d);
        d = fmaf(zf[6], t67[0], d);
        d = fmaf(zf[7], t67[1], d);
        dz[p] = d;
    }

    // exact-equality mask (fp8-unit domain): 4-byte screen, rare full verify
    unsigned mb = 0;
#pragma unroll
    for (int p = 0; p < NPAIR; ++p) {
        unsigned long long ball = __ballot(tv[p].x == cv8.x);
        unsigned blo = (unsigned)ball, bhi = (unsigned)(ball >> 32);
        if (blo == 0xFFFFFFFFu || bhi == 0xFFFFFFFFu) {
            bool full = (tv[p].x == cv8.x) && (tv[p].y == cv8.y);
            unsigned long long b2 = __ballot(full);
            if ((unsigned)b2 == 0xFFFFFFFFu)          mb |= 1u << (1 + 2 * p);
            if ((unsigned)(b2 >> 32) == 0xFFFFFFFFu)  mb |= 1u << (2 + 2 * p);
        }
    }

#pragma unroll
    for (int p = 0; p < NPAIR; ++p) dz[p] = dpp_half_sum(dz[p]);

    // collect: lanes 31/63 deposit pair results (same wave -> in-order DS)
    if (hl == 31) {
#pragma unroll
        for (int p = 0; p < NPAIR; ++p) sd[wid * 32 + 1 + 2 * p + hi] = dz[p];
    }

    // parallel epilogue: lane k (1..20) finishes output k; k=0 written by prep
    if (lane >= 1 && lane < OUTK) {
        float v = sd[wid * 32 + lane] * 2.0f;         // / TEMP, TEMP = 0.5
        if ((mb >> lane) & 1u) v = -INFINITY;
        out[(size_t)bt * OUTK + lane] = v;
    }
}

extern "C" void kernel_launch(void* const* d_in, const int* in_sizes, int n_in,
                              void* d_out, int out_size, void* d_ws, size_t ws_size,
                              hipStream_t stream)
{
    const float* z    = (const float*)d_in[0];
    const float* c    = (const float*)d_in[1];
    const int*   inds = (const int*)d_in[2];
    float* out = (float*)d_out;

    char* ws = (char*)d_ws;
    size_t f16_bytes = (size_t)B_ * T_ * F_ * sizeof(ushort);  // 16 MB
    size_t f8_bytes  = (size_t)B_ * T_ * F_;                   // 8 MB
    ushort* zth = (ushort*)ws;
    unsigned char* zf8 = (unsigned char*)(ws + f16_bytes);
    unsigned char* cf8 = (unsigned char*)(ws + f16_bytes + f8_bytes);

    dim3 tb(256), tg(T_ / 32, B_);
    prep_kernel<<<tg, tb, 0, stream>>>(z, c, zth, zf8, cf8, out);
    sim_kernel<<<dim3(B_ * T_ / 4), dim3(256), 0, stream>>>(zth, zf8, cf8, inds, out);
}

// Round 14
// 46.765 us; speedup vs baseline: 1.1171x; 1.1171x over previous
//
#include <hip/hip_runtime.h>
#include <hip/hip_fp16.h>
#include <math.h>

#define B_ 16
#define F_ 256
#define T_ 2048
#define K_ 20
#define OUTK 21
#define NPAIR 10

typedef _Float16 half2v __attribute__((ext_vector_type(2)));
typedef float v2f __attribute__((ext_vector_type(2)));

#if __has_builtin(__builtin_amdgcn_cvt_pk_f32_fp8) && __has_builtin(__builtin_amdgcn_cvt_pk_fp8_f32)
#define HW_FP8 1
#else
#define HW_FP8 0
#endif

#if !HW_FP8
// fallback e4m3 (OCP) decode/encode — only compiled if HW cvt builtins absent
__device__ __forceinline__ float dec_fp8(unsigned v) {
    unsigned s = (v >> 7) & 1, e = (v >> 3) & 15, m = v & 7;
    float r = e ? __uint_as_float(((e + 120u) << 23) | (m << 20))
                : (float)m * 0.001953125f;  // 2^-9
    return s ? -r : r;
}
__device__ __forceinline__ unsigned enc_fp8(float x) {
    unsigned bits = __float_as_uint(x);
    unsigned s = bits >> 31;
    unsigned a = bits & 0x7fffffffu;
    float ax = __uint_as_float(a);
    unsigned r;
    if (ax < 0.015625f) {                      // subnormal (< 2^-6)
        r = (unsigned)(int)(ax * 512.f + 0.5f);
    } else {
        int e = (int)(a >> 23) - 127;
        unsigned m = a & 0x7fffffu;
        unsigned keep = m >> 20, rest = m & 0xFFFFFu;
        keep += (rest > 0x80000u) || (rest == 0x80000u && (keep & 1));
        if (keep == 8) { keep = 0; ++e; }
        r = ((unsigned)(e + 7) << 3) | keep;
    }
    return (s << 7) | r;
}
#endif

__device__ __forceinline__ unsigned pack_fp8x2(float a0, float a1) {
#if HW_FP8
    return (unsigned)__builtin_amdgcn_cvt_pk_fp8_f32(a0, a1, 0, false) & 0xFFFFu;
#else
    return enc_fp8(a0) | (enc_fp8(a1) << 8);
#endif
}
template <bool HI>
__device__ __forceinline__ v2f unpk_fp8(unsigned u) {
#if HW_FP8
    return __builtin_amdgcn_cvt_pk_f32_fp8((int)u, HI);
#else
    v2f r; unsigned x = HI ? (u >> 16) : u;
    r[0] = dec_fp8(x & 0xFF); r[1] = dec_fp8((x >> 8) & 0xFF);
    return r;
#endif
}

// Prep (r11 structure, single 33.8 KB tile, blockIdx.z selects z/c):
// stage fp32 column-tile, compute exact fp32 1/norm, write unit-norm tables.
// z-branch: zth (f16) + zf8 (fp8 e4m3). c-branch: cf8 (fp8) only.
__global__ __launch_bounds__(256) void prep_kernel(
    const float* __restrict__ z, const float* __restrict__ c,
    ushort* __restrict__ zth, unsigned char* __restrict__ zf8,
    unsigned char* __restrict__ cf8)
{
    __shared__ float tile[256][33];  // 256 f x 32 t, +1 pad
    __shared__ float sc[32];         // per-column 1/norm
    int which = blockIdx.z;
    const float* src = which ? c : z;
    int Lsrc = which ? (T_ + 1) : T_;
    int co   = which;                 // c drops the start token

    int b  = blockIdx.y;
    int t0 = blockIdx.x * 32;
    const float* srcb = src + (size_t)b * F_ * Lsrc;
    int tl = threadIdx.x & 31;
    int fl = threadIdx.x >> 5;
#pragma unroll
    for (int i = 0; i < 32; ++i) {
        int f = i * 8 + fl;
        tile[f][tl] = srcb[(size_t)f * Lsrc + (t0 + tl + co)];
    }
    __syncthreads();
    if (threadIdx.x < 32) {
        float s = 0.f;
#pragma unroll 8
        for (int f = 0; f < 256; ++f) { float v = tile[f][threadIdx.x]; s += v * v; }
        float n = sqrtf(s);
        sc[threadIdx.x] = (n > 0.f) ? (1.0f / n) : 0.f;
    }
    __syncthreads();
    // write phase: 128 lanes cover a row (2 adjacent f each), 2 rows/iter
    int l   = threadIdx.x & 127;
    int rhi = threadIdx.x >> 7;
    if (which == 0) {
#pragma unroll
        for (int j2 = 0; j2 < 16; ++j2) {
            int row = j2 * 2 + rhi;
            float s  = sc[row];
            float a  = tile[2 * l][row] * s;
            float bb = tile[2 * l + 1][row] * s;
            unsigned u = ((unsigned)__half_as_ushort(__float2half(bb)) << 16)
                       |  (unsigned)__half_as_ushort(__float2half(a));
            ((unsigned*)(zth + ((size_t)b * T_ + t0 + row) * F_))[l] = u;
            ((ushort*)(zf8 + ((size_t)b * T_ + t0 + row) * F_))[l] =
                (ushort)pack_fp8x2(a, bb);
        }
    } else {
#pragma unroll
        for (int j2 = 0; j2 < 16; ++j2) {
            int row = j2 * 2 + rhi;
            float s  = sc[row];
            float a  = tile[2 * l][row] * s;
            float bb = tile[2 * l + 1][row] * s;
            ((ushort*)(cf8 + ((size_t)b * T_ + t0 + row) * F_))[l] =
                (ushort)pack_fp8x2(a, bb);
        }
    }
}

// Sum within each 32-lane half (pure VALU DPP). Valid in lane 31 (lo) / 63 (hi).
__device__ __forceinline__ float dpp_half_sum(float x) {
    x += __int_as_float(__builtin_amdgcn_mov_dpp(__float_as_int(x), 0x111, 0xF, 0xF, true)); // row_shr:1
    x += __int_as_float(__builtin_amdgcn_mov_dpp(__float_as_int(x), 0x112, 0xF, 0xF, true)); // row_shr:2
    x += __int_as_float(__builtin_amdgcn_mov_dpp(__float_as_int(x), 0x114, 0xF, 0xF, true)); // row_shr:4
    x += __int_as_float(__builtin_amdgcn_mov_dpp(__float_as_int(x), 0x118, 0xF, 0xF, true)); // row_shr:8
    x += __int_as_float(__builtin_amdgcn_mov_dpp(__float_as_int(x), 0x142, 0xF, 0xF, true)); // row_bcast:15
    return x;
}

// One 64-lane wave per (b,t): 20 negatives as 10 fp8 pair-loads (256 B/row =
// 4 lines). Own z row f16; positive = dot(zv, cv8) — cv8 already loaded for
// the mask, so the positive is compute-only. Parallel lane-k epilogue.
__global__ __launch_bounds__(256, 8) void sim_kernel(
    const ushort* __restrict__ zth, const unsigned char* __restrict__ zf8,
    const unsigned char* __restrict__ cf8, const int* __restrict__ inds,
    float* __restrict__ out)
{
    __shared__ float sd[128];                         // 4 waves x 32 slots
    int i = blockIdx.x;                               // 8192 blocks, 4 waves each
    int b = (i & 7) | ((i >= 4096) ? 8 : 0);          // batch b on XCD b&7 (L2-resident tables)
    int wid = threadIdx.x >> 6;
    int t = (((i >> 3) & 511) << 2) + wid;
    int lane = threadIdx.x & 63;
    int hl = lane & 31;                               // pos within half
    int hi = lane >> 5;                               // which half
    int bt = __builtin_amdgcn_readfirstlane((b << 11) + t);

    const int* myinds = inds + bt * K_;
    int idxv = myinds[(lane < K_) ? lane : 0];        // lane k holds inds[k]

    uint4 zv  = ((const uint4*)(zth + (size_t)bt * F_))[hl];   // own z row (f16)
    uint2 cv8 = ((const uint2*)(cf8 + (size_t)bt * F_))[hl];   // own c row (fp8)

    const char* tbl8 = (const char*)zf8;
    unsigned zbase8  = (unsigned)(b << 11) * 256u;
    unsigned laneoff = (unsigned)hl * 8u;

    uint2 tv[NPAIR];
#pragma unroll
    for (int p = 0; p < NPAIR; ++p) {
        unsigned ilo = (unsigned)__builtin_amdgcn_readlane(idxv, 2 * p);
        unsigned ihi = (unsigned)__builtin_amdgcn_readlane(idxv, 2 * p + 1);
        unsigned off = zbase8 + (hi ? ihi : ilo) * 256u + laneoff;
        tv[p] = *(const uint2*)(tbl8 + off);
    }

    // hard scheduler fence: all 10 pair loads stay issued up-front
    __builtin_amdgcn_sched_barrier(0);

    // zv -> 8 f32 (once per wave-t)
    float zf[8];
    {
        unsigned uu[4] = {zv.x, zv.y, zv.z, zv.w};
#pragma unroll
        for (int q = 0; q < 4; ++q) {
            half2v h = __builtin_bit_cast(half2v, uu[q]);
            zf[2 * q] = (float)h[0]; zf[2 * q + 1] = (float)h[1];
        }
    }

    // positive: dot(zv, cv8) — no extra memory traffic
    float dc;
    {
        v2f c01 = unpk_fp8<false>(cv8.x);
        v2f c23 = unpk_fp8<true >(cv8.x);
        v2f c45 = unpk_fp8<false>(cv8.y);
        v2f c67 = unpk_fp8<true >(cv8.y);
        float d = zf[0] * c01[0];
        d = fmaf(zf[1], c01[1], d);
        d = fmaf(zf[2], c23[0], d);
        d = fmaf(zf[3], c23[1], d);
        d = fmaf(zf[4], c45[0], d);
        d = fmaf(zf[5], c45[1], d);
        d = fmaf(zf[6], c67[0], d);
        d = fmaf(zf[7], c67[1], d);
        dc = d;
    }

    float dz[NPAIR];
#pragma unroll
    for (int p = 0; p < NPAIR; ++p) {
        v2f t01 = unpk_fp8<false>(tv[p].x);
        v2f t23 = unpk_fp8<true >(tv[p].x);
        v2f t45 = unpk_fp8<false>(tv[p].y);
        v2f t67 = unpk_fp8<true >(tv[p].y);
        float d = zf[0] * t01[0];
        d = fmaf(zf[1], t01[1], d);
        d = fmaf(zf[2], t23[0], d);
        d = fmaf(zf[3], t23[1], d);
        d = fmaf(zf[4], t45[0], d);
        d = fmaf(zf[5], t45[1], d);
        d = fmaf(zf[6], t67[0], d);
        d = fmaf(zf[7], t67[1], d);
        dz[p] = d;
    }

    // exact-equality mask (fp8-unit domain): 4-byte screen, rare full verify
    unsigned mb = 0;
#pragma unroll
    for (int p = 0; p < NPAIR; ++p) {
        unsigned long long ball = __ballot(tv[p].x == cv8.x);
        unsigned blo = (unsigned)ball, bhi = (unsigned)(ball >> 32);
        if (blo == 0xFFFFFFFFu || bhi == 0xFFFFFFFFu) {
            bool full = (tv[p].x == cv8.x) && (tv[p].y == cv8.y);
            unsigned long long b2 = __ballot(full);
            if ((unsigned)b2 == 0xFFFFFFFFu)          mb |= 1u << (1 + 2 * p);
            if ((unsigned)(b2 >> 32) == 0xFFFFFFFFu)  mb |= 1u << (2 + 2 * p);
        }
    }

    dc = dpp_half_sum(dc);
#pragma unroll
    for (int p = 0; p < NPAIR; ++p) dz[p] = dpp_half_sum(dz[p]);

    // collect: lanes 31/63 deposit results (same wave -> in-order DS pipe)
    if (hl == 31) {
        if (hi == 0) sd[wid * 32] = dc;
#pragma unroll
        for (int p = 0; p < NPAIR; ++p) sd[wid * 32 + 1 + 2 * p + hi] = dz[p];
    }

    // parallel epilogue: lane k finishes output k (logit = 2 * cosine)
    if (lane < OUTK) {
        float v = sd[wid * 32 + lane] * 2.0f;         // / TEMP, TEMP = 0.5
        if ((mb >> lane) & 1u) v = -INFINITY;
        out[(size_t)bt * OUTK + lane] = v;
    }
}

extern "C" void kernel_launch(void* const* d_in, const int* in_sizes, int n_in,
                              void* d_out, int out_size, void* d_ws, size_t ws_size,
                              hipStream_t stream)
{
    const float* z    = (const float*)d_in[0];
    const float* c    = (const float*)d_in[1];
    const int*   inds = (const int*)d_in[2];
    float* out = (float*)d_out;

    char* ws = (char*)d_ws;
    size_t f16_bytes = (size_t)B_ * T_ * F_ * sizeof(ushort);  // 16 MB
    size_t f8_bytes  = (size_t)B_ * T_ * F_;                   // 8 MB
    ushort* zth = (ushort*)ws;
    unsigned char* zf8 = (unsigned char*)(ws + f16_bytes);
    unsigned char* cf8 = (unsigned char*)(ws + f16_bytes + f8_bytes);

    dim3 tb(256), tg(T_ / 32, B_, 2);
    prep_kernel<<<tg, tb, 0, stream>>>(z, c, zth, zf8, cf8);
    sim_kernel<<<dim3(B_ * T_ / 4), dim3(256), 0, stream>>>(zth, zf8, cf8, inds, out);
}

// Round 15
// 42.517 us; speedup vs baseline: 1.2287x; 1.0999x over previous
//
#include <hip/hip_runtime.h>
#include <hip/hip_fp16.h>
#include <math.h>

#define B_ 16
#define F_ 256
#define T_ 2048
#define K_ 20
#define OUTK 21
#define NPAIR 10

typedef float v2f __attribute__((ext_vector_type(2)));

#if __has_builtin(__builtin_amdgcn_cvt_pk_f32_fp8) && __has_builtin(__builtin_amdgcn_cvt_pk_fp8_f32)
#define HW_FP8 1
#else
#define HW_FP8 0
#endif

#if !HW_FP8
// fallback e4m3 (OCP) decode/encode — only compiled if HW cvt builtins absent
__device__ __forceinline__ float dec_fp8(unsigned v) {
    unsigned s = (v >> 7) & 1, e = (v >> 3) & 15, m = v & 7;
    float r = e ? __uint_as_float(((e + 120u) << 23) | (m << 20))
                : (float)m * 0.001953125f;  // 2^-9
    return s ? -r : r;
}
__device__ __forceinline__ unsigned enc_fp8(float x) {
    unsigned bits = __float_as_uint(x);
    unsigned s = bits >> 31;
    unsigned a = bits & 0x7fffffffu;
    float ax = __uint_as_float(a);
    unsigned r;
    if (ax < 0.015625f) {                      // subnormal (< 2^-6)
        r = (unsigned)(int)(ax * 512.f + 0.5f);
    } else {
        int e = (int)(a >> 23) - 127;
        unsigned m = a & 0x7fffffu;
        unsigned keep = m >> 20, rest = m & 0xFFFFFu;
        keep += (rest > 0x80000u) || (rest == 0x80000u && (keep & 1));
        if (keep == 8) { keep = 0; ++e; }
        r = ((unsigned)(e + 7) << 3) | keep;
    }
    return (s << 7) | r;
}
#endif

__device__ __forceinline__ unsigned pack_fp8x4(float a0, float a1, float a2, float a3) {
#if HW_FP8
    int u = 0;
    u = __builtin_amdgcn_cvt_pk_fp8_f32(a0, a1, u, false);
    u = __builtin_amdgcn_cvt_pk_fp8_f32(a2, a3, u, true);
    return (unsigned)u;
#else
    return enc_fp8(a0) | (enc_fp8(a1) << 8) | (enc_fp8(a2) << 16) | (enc_fp8(a3) << 24);
#endif
}
template <bool HI>
__device__ __forceinline__ v2f unpk_fp8(unsigned u) {
#if HW_FP8
    return __builtin_amdgcn_cvt_pk_f32_fp8((int)u, HI);
#else
    v2f r; unsigned x = HI ? (u >> 16) : u;
    r[0] = dec_fp8(x & 0xFF); r[1] = dec_fp8((x >> 8) & 0xFF);
    return r;
#endif
}

// Prep: stage fp32 column-tile (32 t x 256 f), parallel-compute exact fp32
// 1/norm (all 256 threads), write unit-norm fp8 rows. One 256 B dword-store
// per row per instruction (64 lanes x uint). Identical code for z and c
// (blockIdx.z selects). Row byte-permutation (2j,2j+1,2j+128,2j+129) is
// shared by zf8 and cf8 -> dot & equality invariant.
__global__ __launch_bounds__(256) void prep_kernel(
    const float* __restrict__ z, const float* __restrict__ c,
    unsigned char* __restrict__ zf8, unsigned char* __restrict__ cf8)
{
    __shared__ float tile[256][33];  // 256 f x 32 t, +1 pad
    __shared__ float ps[32][9];      // 8 partial sums per column, +1 pad
    __shared__ float sc[32];         // per-column 1/norm
    int which = blockIdx.z;
    const float* src = which ? c : z;
    unsigned char* dst = which ? cf8 : zf8;
    int Lsrc = which ? (T_ + 1) : T_;
    int co   = which;                 // c drops the start token

    int b  = blockIdx.y;
    int t0 = blockIdx.x * 32;
    const float* srcb = src + (size_t)b * F_ * Lsrc;
    int tl = threadIdx.x & 31;
    int fl = threadIdx.x >> 5;
#pragma unroll
    for (int i = 0; i < 32; ++i) {
        int f = i * 8 + fl;
        tile[f][tl] = srcb[(size_t)f * Lsrc + (t0 + tl + co)];
    }
    __syncthreads();
    // parallel norm: thread (col, oct) sums 32 f-values; fold by 32 threads
    {
        int col = threadIdx.x & 31, oct = threadIdx.x >> 5;
        float s = 0.f;
#pragma unroll 8
        for (int q = 0; q < 32; ++q) {
            float v = tile[oct * 32 + q][col];
            s = fmaf(v, v, s);
        }
        ps[col][oct] = s;
    }
    __syncthreads();
    if (threadIdx.x < 32) {
        float s = 0.f;
#pragma unroll
        for (int o = 0; o < 8; ++o) s += ps[threadIdx.x][o];
        float n = sqrtf(s);
        sc[threadIdx.x] = (n > 0.f) ? (1.0f / n) : 0.f;
    }
    __syncthreads();
    // write: lane j packs 4 values -> uint; 64 lanes = full 256 B row; 4 rows/iter
    {
        int j = threadIdx.x & 63, r4 = threadIdx.x >> 6;
#pragma unroll
        for (int it = 0; it < 8; ++it) {
            int row = it * 4 + r4;
            float s = sc[row];
            unsigned u = pack_fp8x4(tile[2 * j][row] * s, tile[2 * j + 1][row] * s,
                                    tile[2 * j + 128][row] * s, tile[2 * j + 129][row] * s);
            ((unsigned*)(dst + ((size_t)b * T_ + t0 + row) * F_))[j] = u;
        }
    }
}

// Sum within each 32-lane half (pure VALU DPP). Valid in lane 31 (lo) / 63 (hi).
__device__ __forceinline__ float dpp_half_sum(float x) {
    x += __int_as_float(__builtin_amdgcn_mov_dpp(__float_as_int(x), 0x111, 0xF, 0xF, true)); // row_shr:1
    x += __int_as_float(__builtin_amdgcn_mov_dpp(__float_as_int(x), 0x112, 0xF, 0xF, true)); // row_shr:2
    x += __int_as_float(__builtin_amdgcn_mov_dpp(__float_as_int(x), 0x114, 0xF, 0xF, true)); // row_shr:4
    x += __int_as_float(__builtin_amdgcn_mov_dpp(__float_as_int(x), 0x118, 0xF, 0xF, true)); // row_shr:8
    x += __int_as_float(__builtin_amdgcn_mov_dpp(__float_as_int(x), 0x142, 0xF, 0xF, true)); // row_bcast:15
    return x;
}

// One 64-lane wave per (b,t): all rows fp8 (256 B = 4 lines). 20 negatives as
// 10 pair-loads; own z row + c row are 1 wave-load each; positive = dot(z,c)
// in-register. Parallel lane-k epilogue via tiny LDS.
__global__ __launch_bounds__(256, 8) void sim_kernel(
    const unsigned char* __restrict__ zf8, const unsigned char* __restrict__ cf8,
    const int* __restrict__ inds, float* __restrict__ out)
{
    __shared__ float sd[128];                         // 4 waves x 32 slots
    int i = blockIdx.x;                               // 8192 blocks, 4 waves each
    int b = (i & 7) | ((i >= 4096) ? 8 : 0);          // batch b on XCD b&7 (L2-resident tables)
    int wid = threadIdx.x >> 6;
    int t = (((i >> 3) & 511) << 2) + wid;
    int lane = threadIdx.x & 63;
    int hl = lane & 31;                               // pos within half
    int hi = lane >> 5;                               // which half
    int bt = __builtin_amdgcn_readfirstlane((b << 11) + t);

    const int* myinds = inds + bt * K_;
    int idxv = myinds[(lane < K_) ? lane : 0];        // lane k holds inds[k]

    uint2 zv8 = ((const uint2*)(zf8 + (size_t)bt * F_))[hl];   // own z row (fp8)
    uint2 cv8 = ((const uint2*)(cf8 + (size_t)bt * F_))[hl];   // own c row (fp8)

    const char* tbl8 = (const char*)zf8;
    unsigned zbase8  = (unsigned)(b << 11) * 256u;
    unsigned laneoff = (unsigned)hl * 8u;

    uint2 tv[NPAIR];
#pragma unroll
    for (int p = 0; p < NPAIR; ++p) {
        unsigned ilo = (unsigned)__builtin_amdgcn_readlane(idxv, 2 * p);
        unsigned ihi = (unsigned)__builtin_amdgcn_readlane(idxv, 2 * p + 1);
        unsigned off = zbase8 + (hi ? ihi : ilo) * 256u + laneoff;
        tv[p] = *(const uint2*)(tbl8 + off);
    }

    // hard scheduler fence: all 10 pair loads stay issued up-front
    __builtin_amdgcn_sched_barrier(0);

    // own z row -> 8 f32 (once per wave-t)
    float zf[8];
    {
        v2f a01 = unpk_fp8<false>(zv8.x), a23 = unpk_fp8<true>(zv8.x);
        v2f a45 = unpk_fp8<false>(zv8.y), a67 = unpk_fp8<true>(zv8.y);
        zf[0] = a01[0]; zf[1] = a01[1]; zf[2] = a23[0]; zf[3] = a23[1];
        zf[4] = a45[0]; zf[5] = a45[1]; zf[6] = a67[0]; zf[7] = a67[1];
    }

    // positive: dot(z, c) — cv8 already needed for the mask, zero extra traffic
    float dc;
    {
        v2f c01 = unpk_fp8<false>(cv8.x), c23 = unpk_fp8<true>(cv8.x);
        v2f c45 = unpk_fp8<false>(cv8.y), c67 = unpk_fp8<true>(cv8.y);
        float d = zf[0] * c01[0];
        d = fmaf(zf[1], c01[1], d);
        d = fmaf(zf[2], c23[0], d);
        d = fmaf(zf[3], c23[1], d);
        d = fmaf(zf[4], c45[0], d);
        d = fmaf(zf[5], c45[1], d);
        d = fmaf(zf[6], c67[0], d);
        d = fmaf(zf[7], c67[1], d);
        dc = d;
    }

    float dz[NPAIR];
#pragma unroll
    for (int p = 0; p < NPAIR; ++p) {
        v2f t01 = unpk_fp8<false>(tv[p].x), t23 = unpk_fp8<true>(tv[p].x);
        v2f t45 = unpk_fp8<false>(tv[p].y), t67 = unpk_fp8<true>(tv[p].y);
        float d = zf[0] * t01[0];
        d = fmaf(zf[1], t01[1], d);
        d = fmaf(zf[2], t23[0], d);
        d = fmaf(zf[3], t23[1], d);
        d = fmaf(zf[4], t45[0], d);
        d = fmaf(zf[5], t45[1], d);
        d = fmaf(zf[6], t67[0], d);
        d = fmaf(zf[7], t67[1], d);
        dz[p] = d;
    }

    // exact-equality mask (fp8-unit domain): 4-byte screen, rare full verify
    unsigned mb = 0;
#pragma unroll
    for (int p = 0; p < NPAIR; ++p) {
        unsigned long long ball = __ballot(tv[p].x == cv8.x);
        unsigned blo = (unsigned)ball, bhi = (unsigned)(ball >> 32);
        if (blo == 0xFFFFFFFFu || bhi == 0xFFFFFFFFu) {
            bool full = (tv[p].x == cv8.x) && (tv[p].y == cv8.y);
            unsigned long long b2 = __ballot(full);
            if ((unsigned)b2 == 0xFFFFFFFFu)          mb |= 1u << (1 + 2 * p);
            if ((unsigned)(b2 >> 32) == 0xFFFFFFFFu)  mb |= 1u << (2 + 2 * p);
        }
    }

    dc = dpp_half_sum(dc);
#pragma unroll
    for (int p = 0; p < NPAIR; ++p) dz[p] = dpp_half_sum(dz[p]);

    // collect: lanes 31/63 deposit results (same wave -> in-order DS pipe)
    if (hl == 31) {
        if (hi == 0) sd[wid * 32] = dc;
#pragma unroll
        for (int p = 0; p < NPAIR; ++p) sd[wid * 32 + 1 + 2 * p + hi] = dz[p];
    }

    // parallel epilogue: lane k finishes output k (logit = 2 * cosine)
    if (lane < OUTK) {
        float v = sd[wid * 32 + lane] * 2.0f;         // / TEMP, TEMP = 0.5
        if ((mb >> lane) & 1u) v = -INFINITY;
        out[(size_t)bt * OUTK + lane] = v;
    }
}

extern "C" void kernel_launch(void* const* d_in, const int* in_sizes, int n_in,
                              void* d_out, int out_size, void* d_ws, size_t ws_size,
                              hipStream_t stream)
{
    const float* z    = (const float*)d_in[0];
    const float* c    = (const float*)d_in[1];
    const int*   inds = (const int*)d_in[2];
    float* out = (float*)d_out;

    char* ws = (char*)d_ws;
    size_t f8_bytes = (size_t)B_ * T_ * F_;                    // 8 MB
    unsigned char* zf8 = (unsigned char*)ws;
    unsigned char* cf8 = (unsigned char*)(ws + f8_bytes);

    dim3 tb(256), tg(T_ / 32, B_, 2);
    prep_kernel<<<tg, tb, 0, stream>>>(z, c, zf8, cf8);
    sim_kernel<<<dim3(B_ * T_ / 4), dim3(256), 0, stream>>>(zf8, cf8, inds, out);
}

// Round 16
// 42.389 us; speedup vs baseline: 1.2324x; 1.0030x over previous
//
#include <hip/hip_runtime.h>
#include <hip/hip_fp16.h>
#include <math.h>

#define B_ 16
#define F_ 256
#define T_ 2048
#define K_ 20
#define OUTK 21
#define NPAIR 10

typedef float v2f __attribute__((ext_vector_type(2)));

#if __has_builtin(__builtin_amdgcn_cvt_pk_f32_fp8) && __has_builtin(__builtin_amdgcn_cvt_pk_fp8_f32)
#define HW_FP8 1
#else
#define HW_FP8 0
#endif

#if !HW_FP8
// fallback e4m3 (OCP) decode/encode — only compiled if HW cvt builtins absent
__device__ __forceinline__ float dec_fp8(unsigned v) {
    unsigned s = (v >> 7) & 1, e = (v >> 3) & 15, m = v & 7;
    float r = e ? __uint_as_float(((e + 120u) << 23) | (m << 20))
                : (float)m * 0.001953125f;  // 2^-9
    return s ? -r : r;
}
__device__ __forceinline__ unsigned enc_fp8(float x) {
    unsigned bits = __float_as_uint(x);
    unsigned s = bits >> 31;
    unsigned a = bits & 0x7fffffffu;
    float ax = __uint_as_float(a);
    unsigned r;
    if (ax < 0.015625f) {                      // subnormal (< 2^-6)
        r = (unsigned)(int)(ax * 512.f + 0.5f);
    } else {
        int e = (int)(a >> 23) - 127;
        unsigned m = a & 0x7fffffu;
        unsigned keep = m >> 20, rest = m & 0xFFFFFu;
        keep += (rest > 0x80000u) || (rest == 0x80000u && (keep & 1));
        if (keep == 8) { keep = 0; ++e; }
        r = ((unsigned)(e + 7) << 3) | keep;
    }
    return (s << 7) | r;
}
#endif

__device__ __forceinline__ unsigned pack_fp8x4(float a0, float a1, float a2, float a3) {
#if HW_FP8
    int u = 0;
    u = __builtin_amdgcn_cvt_pk_fp8_f32(a0, a1, u, false);
    u = __builtin_amdgcn_cvt_pk_fp8_f32(a2, a3, u, true);
    return (unsigned)u;
#else
    return enc_fp8(a0) | (enc_fp8(a1) << 8) | (enc_fp8(a2) << 16) | (enc_fp8(a3) << 24);
#endif
}
template <bool HI>
__device__ __forceinline__ v2f unpk_fp8(unsigned u) {
#if HW_FP8
    return __builtin_amdgcn_cvt_pk_f32_fp8((int)u, HI);
#else
    v2f r; unsigned x = HI ? (u >> 16) : u;
    r[0] = dec_fp8(x & 0xFF); r[1] = dec_fp8((x >> 8) & 0xFF);
    return r;
#endif
}

// Prep: stage fp32 column-tile (32 t x 256 f), parallel exact-fp32 1/norm,
// write unit-norm fp8 rows (256 B dword stores). z-branch loads float4
// (16 B/lane, rows 16B-aligned since T=2048); c-branch keeps scalar dword
// loads (Lsrc=2049 odd -> rows unalignable). Same math as r15 -> identical
// output bits.
__global__ __launch_bounds__(256) void prep_kernel(
    const float* __restrict__ z, const float* __restrict__ c,
    unsigned char* __restrict__ zf8, unsigned char* __restrict__ cf8)
{
    __shared__ float tile[256][33];  // 256 f x 32 t, +1 pad
    __shared__ float ps[32][9];      // 8 partial sums per column, +1 pad
    __shared__ float sc[32];         // per-column 1/norm
    int which = blockIdx.z;
    unsigned char* dst = which ? cf8 : zf8;

    int b  = blockIdx.y;
    int t0 = blockIdx.x * 32;

    if (which == 0) {
        // z: float4 loads — 8 iters, f = i*32 + (tid>>3), t-quad q = tid&7
        const float* zb = z + (size_t)b * F_ * T_ + t0;
        int q  = threadIdx.x & 7;
        int fo = threadIdx.x >> 3;
#pragma unroll
        for (int i = 0; i < 8; ++i) {
            int f = i * 32 + fo;
            float4 v = *(const float4*)(zb + (size_t)f * T_ + 4 * q);
            tile[f][4 * q + 0] = v.x;
            tile[f][4 * q + 1] = v.y;
            tile[f][4 * q + 2] = v.z;
            tile[f][4 * q + 3] = v.w;
        }
    } else {
        // c: scalar loads (misaligned rows), drop start token (co=1)
        const float* cb = c + (size_t)b * F_ * (T_ + 1);
        int tl = threadIdx.x & 31;
        int fl = threadIdx.x >> 5;
#pragma unroll
        for (int i = 0; i < 32; ++i) {
            int f = i * 8 + fl;
            tile[f][tl] = cb[(size_t)f * (T_ + 1) + (t0 + tl + 1)];
        }
    }
    __syncthreads();
    // parallel norm: thread (col, oct) sums 32 f-values; fold by 32 threads
    {
        int col = threadIdx.x & 31, oct = threadIdx.x >> 5;
        float s = 0.f;
#pragma unroll 8
        for (int qq = 0; qq < 32; ++qq) {
            float v = tile[oct * 32 + qq][col];
            s = fmaf(v, v, s);
        }
        ps[col][oct] = s;
    }
    __syncthreads();
    if (threadIdx.x < 32) {
        float s = 0.f;
#pragma unroll
        for (int o = 0; o < 8; ++o) s += ps[threadIdx.x][o];
        float n = sqrtf(s);
        sc[threadIdx.x] = (n > 0.f) ? (1.0f / n) : 0.f;
    }
    __syncthreads();
    // write: lane j packs 4 values -> uint; 64 lanes = full 256 B row; 4 rows/iter
    {
        int j = threadIdx.x & 63, r4 = threadIdx.x >> 6;
#pragma unroll
        for (int it = 0; it < 8; ++it) {
            int row = it * 4 + r4;
            float s = sc[row];
            unsigned u = pack_fp8x4(tile[2 * j][row] * s, tile[2 * j + 1][row] * s,
                                    tile[2 * j + 128][row] * s, tile[2 * j + 129][row] * s);
            ((unsigned*)(dst + ((size_t)b * T_ + t0 + row) * F_))[j] = u;
        }
    }
}

// Sum within each 32-lane half (pure VALU DPP). Valid in lane 31 (lo) / 63 (hi).
__device__ __forceinline__ float dpp_half_sum(float x) {
    x += __int_as_float(__builtin_amdgcn_mov_dpp(__float_as_int(x), 0x111, 0xF, 0xF, true)); // row_shr:1
    x += __int_as_float(__builtin_amdgcn_mov_dpp(__float_as_int(x), 0x112, 0xF, 0xF, true)); // row_shr:2
    x += __int_as_float(__builtin_amdgcn_mov_dpp(__float_as_int(x), 0x114, 0xF, 0xF, true)); // row_shr:4
    x += __int_as_float(__builtin_amdgcn_mov_dpp(__float_as_int(x), 0x118, 0xF, 0xF, true)); // row_shr:8
    x += __int_as_float(__builtin_amdgcn_mov_dpp(__float_as_int(x), 0x142, 0xF, 0xF, true)); // row_bcast:15
    return x;
}

// One 64-lane wave per (b,t): all rows fp8 (256 B = 4 lines). 20 negatives as
// 10 pair-loads; own z row + c row are 1 wave-load each; positive = dot(z,c)
// in-register. Parallel lane-k epilogue via tiny LDS.
__global__ __launch_bounds__(256, 8) void sim_kernel(
    const unsigned char* __restrict__ zf8, const unsigned char* __restrict__ cf8,
    const int* __restrict__ inds, float* __restrict__ out)
{
    __shared__ float sd[128];                         // 4 waves x 32 slots
    int i = blockIdx.x;                               // 8192 blocks, 4 waves each
    int b = (i & 7) | ((i >= 4096) ? 8 : 0);          // batch b on XCD b&7 (L2-resident tables)
    int wid = threadIdx.x >> 6;
    int t = (((i >> 3) & 511) << 2) + wid;
    int lane = threadIdx.x & 63;
    int hl = lane & 31;                               // pos within half
    int hi = lane >> 5;                               // which half
    int bt = __builtin_amdgcn_readfirstlane((b << 11) + t);

    const int* myinds = inds + bt * K_;
    int idxv = myinds[(lane < K_) ? lane : 0];        // lane k holds inds[k]

    uint2 zv8 = ((const uint2*)(zf8 + (size_t)bt * F_))[hl];   // own z row (fp8)
    uint2 cv8 = ((const uint2*)(cf8 + (size_t)bt * F_))[hl];   // own c row (fp8)

    const char* tbl8 = (const char*)zf8;
    unsigned zbase8  = (unsigned)(b << 11) * 256u;
    unsigned laneoff = (unsigned)hl * 8u;

    uint2 tv[NPAIR];
#pragma unroll
    for (int p = 0; p < NPAIR; ++p) {
        unsigned ilo = (unsigned)__builtin_amdgcn_readlane(idxv, 2 * p);
        unsigned ihi = (unsigned)__builtin_amdgcn_readlane(idxv, 2 * p + 1);
        unsigned off = zbase8 + (hi ? ihi : ilo) * 256u + laneoff;
        tv[p] = *(const uint2*)(tbl8 + off);
    }

    // hard scheduler fence: all 10 pair loads stay issued up-front
    __builtin_amdgcn_sched_barrier(0);

    // own z row -> 8 f32 (once per wave-t)
    float zf[8];
    {
        v2f a01 = unpk_fp8<false>(zv8.x), a23 = unpk_fp8<true>(zv8.x);
        v2f a45 = unpk_fp8<false>(zv8.y), a67 = unpk_fp8<true>(zv8.y);
        zf[0] = a01[0]; zf[1] = a01[1]; zf[2] = a23[0]; zf[3] = a23[1];
        zf[4] = a45[0]; zf[5] = a45[1]; zf[6] = a67[0]; zf[7] = a67[1];
    }

    // positive: dot(z, c) — cv8 already needed for the mask, zero extra traffic
    float dc;
    {
        v2f c01 = unpk_fp8<false>(cv8.x), c23 = unpk_fp8<true>(cv8.x);
        v2f c45 = unpk_fp8<false>(cv8.y), c67 = unpk_fp8<true>(cv8.y);
        float d = zf[0] * c01[0];
        d = fmaf(zf[1], c01[1], d);
        d = fmaf(zf[2], c23[0], d);
        d = fmaf(zf[3], c23[1], d);
        d = fmaf(zf[4], c45[0], d);
        d = fmaf(zf[5], c45[1], d);
        d = fmaf(zf[6], c67[0], d);
        d = fmaf(zf[7], c67[1], d);
        dc = d;
    }

    float dz[NPAIR];
#pragma unroll
    for (int p = 0; p < NPAIR; ++p) {
        v2f t01 = unpk_fp8<false>(tv[p].x), t23 = unpk_fp8<true>(tv[p].x);
        v2f t45 = unpk_fp8<false>(tv[p].y), t67 = unpk_fp8<true>(tv[p].y);
        float d = zf[0] * t01[0];
        d = fmaf(zf[1], t01[1], d);
        d = fmaf(zf[2], t23[0], d);
        d = fmaf(zf[3], t23[1], d);
        d = fmaf(zf[4], t45[0], d);
        d = fmaf(zf[5], t45[1], d);
        d = fmaf(zf[6], t67[0], d);
        d = fmaf(zf[7], t67[1], d);
        dz[p] = d;
    }

    // exact-equality mask (fp8-unit domain): 4-byte screen, rare full verify
    unsigned mb = 0;
#pragma unroll
    for (int p = 0; p < NPAIR; ++p) {
        unsigned long long ball = __ballot(tv[p].x == cv8.x);
        unsigned blo = (unsigned)ball, bhi = (unsigned)(ball >> 32);
        if (blo == 0xFFFFFFFFu || bhi == 0xFFFFFFFFu) {
            bool full = (tv[p].x == cv8.x) && (tv[p].y == cv8.y);
            unsigned long long b2 = __ballot(full);
            if ((unsigned)b2 == 0xFFFFFFFFu)          mb |= 1u << (1 + 2 * p);
            if ((unsigned)(b2 >> 32) == 0xFFFFFFFFu)  mb |= 1u << (2 + 2 * p);
        }
    }

    dc = dpp_half_sum(dc);
#pragma unroll
    for (int p = 0; p < NPAIR; ++p) dz[p] = dpp_half_sum(dz[p]);

    // collect: lanes 31/63 deposit results (same wave -> in-order DS pipe)
    if (hl == 31) {
        if (hi == 0) sd[wid * 32] = dc;
#pragma unroll
        for (int p = 0; p < NPAIR; ++p) sd[wid * 32 + 1 + 2 * p + hi] = dz[p];
    }

    // parallel epilogue: lane k finishes output k (logit = 2 * cosine)
    if (lane < OUTK) {
        float v = sd[wid * 32 + lane] * 2.0f;         // / TEMP, TEMP = 0.5
        if ((mb >> lane) & 1u) v = -INFINITY;
        out[(size_t)bt * OUTK + lane] = v;
    }
}

extern "C" void kernel_launch(void* const* d_in, const int* in_sizes, int n_in,
                              void* d_out, int out_size, void* d_ws, size_t ws_size,
                              hipStream_t stream)
{
    const float* z    = (const float*)d_in[0];
    const float* c    = (const float*)d_in[1];
    const int*   inds = (const int*)d_in[2];
    float* out = (float*)d_out;

    char* ws = (char*)d_ws;
    size_t f8_bytes = (size_t)B_ * T_ * F_;                    // 8 MB
    unsigned char* zf8 = (unsigned char*)ws;
    unsigned char* cf8 = (unsigned char*)(ws + f8_bytes);

    dim3 tb(256), tg(T_ / 32, B_, 2);
    prep_kernel<<<tg, tb, 0, stream>>>(z, c, zf8, cf8);
    sim_kernel<<<dim3(B_ * T_ / 4), dim3(256), 0, stream>>>(zf8, cf8, inds, out);
}